// Round 1
// baseline (239.310 us; speedup 1.0000x reference)
//
#include <hip/hip_runtime.h>
#include <hip/hip_bf16.h>
#include <math.h>

// Chamfer distance, B=8, N=M=8192, D=3, fp32.
// Strategy: brute-force NN in both directions.
//   d2(i,j) = ||q_i||^2 + ||r_j||^2 - 2 q_i.r_j
//   min_j d2 = ||q_i||^2 + 2 * min_j ( 0.5*||r_j||^2 - q_i.r_j )
// Inner loop per pair: mul + 2 fma + sub + min = 5 VALU instrs.
// Partial mins across M-chunks merged with atomicMin on order-preserving
// uint encoding of float.

#define BLOCK 256
#define TM 512        // reference points staged per LDS tile
#define NCHUNK 4      // split of reference dim across blockIdx.y
#define QPT 2         // queries per thread

__device__ __forceinline__ unsigned int encodeKey(float f) {
    unsigned int u = __float_as_uint(f);
    return (u & 0x80000000u) ? ~u : (u | 0x80000000u);
}
__device__ __forceinline__ float decodeKey(unsigned int u) {
    u = (u & 0x80000000u) ? (u & 0x7FFFFFFFu) : ~u;
    return __uint_as_float(u);
}

// Fill keys with "+inf" encoding; zero the scalar output.
__global__ void init_kernel(unsigned int* keys, int total, float* out) {
    int idx = blockIdx.x * blockDim.x + threadIdx.x;
    if (idx < total) keys[idx] = 0xFFFFFFFFu;
    if (idx == 0) out[0] = 0.0f;
}

// For each query point (b,i) in Q[B,NQ,3], partial min over a chunk of
// R[B,NR,3] of key = 0.5*||r||^2 - q.r ; atomicMin into keyBits[b*NQ+i].
__global__ void __launch_bounds__(BLOCK)
nn_min_kernel(const float* __restrict__ Q, const float* __restrict__ R,
              unsigned int* __restrict__ keyBits, int NQ, int NR, int chunkSize) {
    const int b = blockIdx.z;
    const int tid = threadIdx.x;
    const int i0 = (blockIdx.x * BLOCK + tid) * QPT;
    const float* Qb = Q + (size_t)b * NQ * 3;
    const float* Rb = R + (size_t)b * NR * 3;

    const bool v0 = (i0 + 0) < NQ;
    const bool v1 = (i0 + 1) < NQ;
    float q0x = 0.f, q0y = 0.f, q0z = 0.f;
    float q1x = 0.f, q1y = 0.f, q1z = 0.f;
    if (v0) { q0x = Qb[i0 * 3 + 0]; q0y = Qb[i0 * 3 + 1]; q0z = Qb[i0 * 3 + 2]; }
    if (v1) { q1x = Qb[i0 * 3 + 3]; q1y = Qb[i0 * 3 + 4]; q1z = Qb[i0 * 3 + 5]; }

    float k0 = INFINITY, k1 = INFINITY;

    __shared__ float4 sR[TM];

    const int chunkStart = blockIdx.y * chunkSize;
    const int chunkEnd   = min(chunkStart + chunkSize, NR);

    for (int t0 = chunkStart; t0 < chunkEnd; t0 += TM) {
        const int cnt = min(TM, chunkEnd - t0);
        for (int p = tid; p < cnt; p += BLOCK) {
            const float rx = Rb[(t0 + p) * 3 + 0];
            const float ry = Rb[(t0 + p) * 3 + 1];
            const float rz = Rb[(t0 + p) * 3 + 2];
            sR[p] = make_float4(rx, ry, rz, 0.5f * (rx * rx + ry * ry + rz * rz));
        }
        __syncthreads();
        #pragma unroll 4
        for (int j = 0; j < cnt; ++j) {
            const float4 r = sR[j];
            const float d0 = r.w - (q0x * r.x + q0y * r.y + q0z * r.z);
            const float d1 = r.w - (q1x * r.x + q1y * r.y + q1z * r.z);
            k0 = fminf(k0, d0);
            k1 = fminf(k1, d1);
        }
        __syncthreads();
    }

    if (v0) atomicMin(&keyBits[(size_t)b * NQ + i0 + 0], encodeKey(k0));
    if (v1) atomicMin(&keyBits[(size_t)b * NQ + i0 + 1], encodeKey(k1));
}

// Sum both directions: d2 = max(0, 2*key + ||q||^2), weighted means, atomicAdd.
__global__ void __launch_bounds__(BLOCK)
reduce_kernel(const unsigned int* __restrict__ keyx, const float* __restrict__ gts, int totalx,
              const unsigned int* __restrict__ keyy, const float* __restrict__ preds, int totaly,
              float invx, float invy, float* __restrict__ out) {
    const int total = totalx + totaly;
    float local = 0.0f;
    for (int idx = blockIdx.x * blockDim.x + threadIdx.x; idx < total;
         idx += gridDim.x * blockDim.x) {
        if (idx < totalx) {
            const float k = decodeKey(keyx[idx]);
            const float* p = gts + (size_t)idx * 3;
            const float x2 = p[0] * p[0] + p[1] * p[1] + p[2] * p[2];
            local += fmaxf(2.0f * k + x2, 0.0f) * invx;
        } else {
            const int j = idx - totalx;
            const float k = decodeKey(keyy[j]);
            const float* p = preds + (size_t)j * 3;
            const float y2 = p[0] * p[0] + p[1] * p[1] + p[2] * p[2];
            local += fmaxf(2.0f * k + y2, 0.0f) * invy;
        }
    }
    // wave reduce (64 lanes) then cross-wave via LDS, one atomicAdd per block
    __shared__ float waveSums[BLOCK / 64];
    float v = local;
    #pragma unroll
    for (int off = 32; off > 0; off >>= 1) v += __shfl_down(v, off, 64);
    const int lane = threadIdx.x & 63;
    const int wave = threadIdx.x >> 6;
    if (lane == 0) waveSums[wave] = v;
    __syncthreads();
    if (threadIdx.x == 0) {
        float s = 0.0f;
        #pragma unroll
        for (int w = 0; w < BLOCK / 64; ++w) s += waveSums[w];
        atomicAdd(out, s);
    }
}

extern "C" void kernel_launch(void* const* d_in, const int* in_sizes, int n_in,
                              void* d_out, int out_size, void* d_ws, size_t ws_size,
                              hipStream_t stream) {
    const float* gts   = (const float*)d_in[0];   // [B, N, 3]
    const float* preds = (const float*)d_in[1];   // [B, M, 3]
    float* out = (float*)d_out;

    const int B = 8;
    const int N = in_sizes[0] / (B * 3);
    const int M = in_sizes[1] / (B * 3);

    unsigned int* keyx = (unsigned int*)d_ws;           // B*N entries
    unsigned int* keyy = keyx + (size_t)B * N;          // B*M entries

    const int totalKeys = B * N + B * M;

    // 1) init keys to +inf encoding, zero output scalar
    init_kernel<<<(totalKeys + BLOCK - 1) / BLOCK, BLOCK, 0, stream>>>(keyx, totalKeys, out);

    // 2) direction x->y : queries = gts, refs = preds
    {
        const int chunk = (M + NCHUNK - 1) / NCHUNK;
        dim3 grid((N + BLOCK * QPT - 1) / (BLOCK * QPT), NCHUNK, B);
        nn_min_kernel<<<grid, BLOCK, 0, stream>>>(gts, preds, keyx, N, M, chunk);
    }
    // 3) direction y->x : queries = preds, refs = gts
    {
        const int chunk = (N + NCHUNK - 1) / NCHUNK;
        dim3 grid((M + BLOCK * QPT - 1) / (BLOCK * QPT), NCHUNK, B);
        nn_min_kernel<<<grid, BLOCK, 0, stream>>>(preds, gts, keyy, M, N, chunk);
    }

    // 4) reduce to scalar
    const float invx = 1.0f / (float)((size_t)B * N);
    const float invy = 1.0f / (float)((size_t)B * M);
    reduce_kernel<<<256, BLOCK, 0, stream>>>(keyx, gts, B * N, keyy, preds, B * M,
                                             invx, invy, out);
}

// Round 2
// 148.717 us; speedup vs baseline: 1.6092x; 1.6092x over previous
//
#include <hip/hip_runtime.h>
#include <hip/hip_bf16.h>
#include <math.h>

// Chamfer distance, B=8, N=M=8192, D=3, fp32.
//   min_j d2 = ||q||^2 + 2 * min_j ( 0.5*||r_j||^2 - q.r_j )
// Inner loop: v_pk_fma_f32 packed across j-pairs:
//   acc = pk_fma(-q.x, (x_j0,x_j1), (w_j0,w_j1)); acc = pk_fma(-q.y, (y..), acc);
//   acc = pk_fma(-q.z, (z..), acc); k = min3(acc.lo, acc.hi, k)
// => 4 instr per (query, j-pair) = 2 instr/pair. Partial mins across ref
// chunks merged via atomicMin on order-preserving uint keys.

#define BLOCK 256
#define TM 1024       // reference points per chunk (= per block), LDS-resident
#define QPT 4         // queries per thread

typedef float v2f __attribute__((ext_vector_type(2)));

__device__ __forceinline__ v2f pk_fma(v2f a, v2f b, v2f c) {
    v2f d;
    asm("v_pk_fma_f32 %0, %1, %2, %3" : "=v"(d) : "v"(a), "v"(b), "v"(c));
    return d;
}

__device__ __forceinline__ unsigned int encodeKey(float f) {
    unsigned int u = __float_as_uint(f);
    return (u & 0x80000000u) ? ~u : (u | 0x80000000u);
}
__device__ __forceinline__ float decodeKey(unsigned int u) {
    u = (u & 0x80000000u) ? (u & 0x7FFFFFFFu) : ~u;
    return __uint_as_float(u);
}

__global__ void init_kernel(unsigned int* keys, int total, float* out) {
    int idx = blockIdx.x * blockDim.x + threadIdx.x;
    if (idx < total) keys[idx] = 0xFFFFFFFFu;
    if (idx == 0) out[0] = 0.0f;
}

// Both directions in one launch: blockIdx.z in [0, 2B). z<B: Q=gts, R=preds,
// keys=keyx; else Q=preds, R=gts, keys=keyy.
__global__ void __launch_bounds__(BLOCK)
nn_min_kernel(const float* __restrict__ gts, const float* __restrict__ preds,
              unsigned int* __restrict__ keyx, unsigned int* __restrict__ keyy,
              int N, int M, int B) {
    const int z = blockIdx.z;
    const bool dirX = (z < B);
    const int b = dirX ? z : z - B;
    const int NQ = dirX ? N : M;
    const int NR = dirX ? M : N;
    const float* Qb = (dirX ? gts : preds) + (size_t)b * NQ * 3;
    const float* Rb = (dirX ? preds : gts) + (size_t)b * NR * 3;
    unsigned int* keys = (dirX ? keyx : keyy) + (size_t)b * NQ;

    const int tid = threadIdx.x;
    const int qBase = blockIdx.x * (BLOCK * QPT);
    if (qBase >= NQ) return;                 // uniform
    const int chunkStart = blockIdx.y * TM;
    if (chunkStart >= NR) return;            // uniform
    const int cnt = min(TM, NR - chunkStart);

    // ---- stage refs pair-transposed into LDS: sX[p]=x_p etc., pairs read as v2f
    __shared__ __align__(16) float sRef[4 * TM];   // [X | Y | Z | W] 16 KB
    const int cntPad = (cnt + 1) & ~1;
    for (int p = tid; p < cntPad; p += BLOCK) {
        float rx = 0.f, ry = 0.f, rz = 0.f, w = INFINITY;
        if (p < cnt) {
            rx = Rb[(chunkStart + p) * 3 + 0];
            ry = Rb[(chunkStart + p) * 3 + 1];
            rz = Rb[(chunkStart + p) * 3 + 2];
            w  = 0.5f * (rx * rx + ry * ry + rz * rz);
        }
        sRef[p]          = rx;
        sRef[TM + p]     = ry;
        sRef[2 * TM + p] = rz;
        sRef[3 * TM + p] = w;
    }

    // ---- per-thread query coefficients, negated + duplicated into both halves
    int   qi[QPT];
    bool  qv[QPT];
    v2f   nqx[QPT], nqy[QPT], nqz[QPT];
    #pragma unroll
    for (int q = 0; q < QPT; ++q) {
        qi[q] = qBase + q * BLOCK + tid;
        qv[q] = qi[q] < NQ;
        float qx = 0.f, qy = 0.f, qz = 0.f;
        if (qv[q]) {
            qx = Qb[qi[q] * 3 + 0];
            qy = Qb[qi[q] * 3 + 1];
            qz = Qb[qi[q] * 3 + 2];
        }
        nqx[q] = (v2f){-qx, -qx};
        nqy[q] = (v2f){-qy, -qy};
        nqz[q] = (v2f){-qz, -qz};
    }

    __syncthreads();

    const v2f* pX = (const v2f*)(sRef);
    const v2f* pY = (const v2f*)(sRef + TM);
    const v2f* pZ = (const v2f*)(sRef + 2 * TM);
    const v2f* pW = (const v2f*)(sRef + 3 * TM);

    float k[QPT];
    #pragma unroll
    for (int q = 0; q < QPT; ++q) k[q] = INFINITY;

    const int nPairs = cntPad >> 1;
    #pragma unroll 4
    for (int jp = 0; jp < nPairs; ++jp) {
        const v2f xj = pX[jp];
        const v2f yj = pY[jp];
        const v2f zj = pZ[jp];
        const v2f wj = pW[jp];
        #pragma unroll
        for (int q = 0; q < QPT; ++q) {
            v2f acc = pk_fma(nqx[q], xj, wj);
            acc = pk_fma(nqy[q], yj, acc);
            acc = pk_fma(nqz[q], zj, acc);
            k[q] = fminf(fminf(acc.x, acc.y), k[q]);   // -> v_min3_f32
        }
    }

    #pragma unroll
    for (int q = 0; q < QPT; ++q)
        if (qv[q]) atomicMin(&keys[qi[q]], encodeKey(k[q]));
}

__global__ void __launch_bounds__(BLOCK)
reduce_kernel(const unsigned int* __restrict__ keyx, const float* __restrict__ gts, int totalx,
              const unsigned int* __restrict__ keyy, const float* __restrict__ preds, int totaly,
              float invx, float invy, float* __restrict__ out) {
    const int total = totalx + totaly;
    float local = 0.0f;
    for (int idx = blockIdx.x * blockDim.x + threadIdx.x; idx < total;
         idx += gridDim.x * blockDim.x) {
        if (idx < totalx) {
            const float kk = decodeKey(keyx[idx]);
            const float* p = gts + (size_t)idx * 3;
            const float x2 = p[0] * p[0] + p[1] * p[1] + p[2] * p[2];
            local += fmaxf(2.0f * kk + x2, 0.0f) * invx;
        } else {
            const int j = idx - totalx;
            const float kk = decodeKey(keyy[j]);
            const float* p = preds + (size_t)j * 3;
            const float y2 = p[0] * p[0] + p[1] * p[1] + p[2] * p[2];
            local += fmaxf(2.0f * kk + y2, 0.0f) * invy;
        }
    }
    __shared__ float waveSums[BLOCK / 64];
    float v = local;
    #pragma unroll
    for (int off = 32; off > 0; off >>= 1) v += __shfl_down(v, off, 64);
    const int lane = threadIdx.x & 63;
    const int wave = threadIdx.x >> 6;
    if (lane == 0) waveSums[wave] = v;
    __syncthreads();
    if (threadIdx.x == 0) {
        float s = 0.0f;
        #pragma unroll
        for (int w = 0; w < BLOCK / 64; ++w) s += waveSums[w];
        atomicAdd(out, s);
    }
}

extern "C" void kernel_launch(void* const* d_in, const int* in_sizes, int n_in,
                              void* d_out, int out_size, void* d_ws, size_t ws_size,
                              hipStream_t stream) {
    const float* gts   = (const float*)d_in[0];   // [B, N, 3]
    const float* preds = (const float*)d_in[1];   // [B, M, 3]
    float* out = (float*)d_out;

    const int B = 8;
    const int N = in_sizes[0] / (B * 3);
    const int M = in_sizes[1] / (B * 3);

    unsigned int* keyx = (unsigned int*)d_ws;     // B*N entries
    unsigned int* keyy = keyx + (size_t)B * N;    // B*M entries
    const int totalKeys = B * N + B * M;

    init_kernel<<<(totalKeys + BLOCK - 1) / BLOCK, BLOCK, 0, stream>>>(keyx, totalKeys, out);

    const int maxQ = max(N, M);
    const int maxR = max(N, M);
    dim3 grid((maxQ + BLOCK * QPT - 1) / (BLOCK * QPT),
              (maxR + TM - 1) / TM,
              2 * B);
    nn_min_kernel<<<grid, BLOCK, 0, stream>>>(gts, preds, keyx, keyy, N, M, B);

    const float invx = 1.0f / (float)((size_t)B * N);
    const float invy = 1.0f / (float)((size_t)B * M);
    reduce_kernel<<<256, BLOCK, 0, stream>>>(keyx, gts, B * N, keyy, preds, B * M,
                                             invx, invy, out);
}